// Round 5
// baseline (420.379 us; speedup 1.0000x reference)
//
#include <hip/hip_runtime.h>
#include <stdint.h>

#define D_DIM 256
#define NPAD  640   // 256 (W_lin) + 256 (W_res) + 8 (att_l) + 8 (att_r) + 112 zero pad -> 5 x 128 tiles

typedef __bf16 bf16x8 __attribute__((ext_vector_type(8)));
typedef float  f32x4  __attribute__((ext_vector_type(4)));

__device__ __forceinline__ float bf2f(unsigned short u) {
  union { unsigned int i; float f; } cv; cv.i = ((unsigned int)u) << 16; return cv.f;
}
__device__ __forceinline__ unsigned short f2bf(float f) {
  union { float f; unsigned int i; } cv; cv.f = f;
  unsigned int i = cv.i;
  unsigned int lsb = (i >> 16) & 1u;
  i += 0x7fffu + lsb;   // round-to-nearest-even
  return (unsigned short)(i >> 16);
}
__device__ __forceinline__ void gld16(const void* gptr, void* lptr) {
  __builtin_amdgcn_global_load_lds(
      (const __attribute__((address_space(1))) unsigned int*)gptr,
      (__attribute__((address_space(3))) unsigned int*)lptr, 16, 0, 0);
}

// ---------------- setup: [cvt_feat | prep_bt] by block range ----------------
__global__ __launch_bounds__(256) void setup_cvt_prep(
    const float* __restrict__ feat, unsigned short* __restrict__ fb,
    const float* __restrict__ W_lin, const float* __restrict__ W_res,
    const float* __restrict__ att_l, const float* __restrict__ att_r,
    unsigned short* __restrict__ Bt, int nelem, int nb_cvt) {
  int bid = blockIdx.x, t = threadIdx.x;
  if (bid < nb_cvt) {
    int i = (bid * 256 + t) * 8;
    if (i >= nelem) return;
    float4 v0 = *(const float4*)(feat + i);
    float4 v1 = *(const float4*)(feat + i + 4);
    ushort4 a, b;
    a.x = f2bf(v0.x); a.y = f2bf(v0.y); a.z = f2bf(v0.z); a.w = f2bf(v0.w);
    b.x = f2bf(v1.x); b.y = f2bf(v1.y); b.z = f2bf(v1.z); b.w = f2bf(v1.w);
    *(ushort4*)(fb + i) = a;
    *(ushort4*)(fb + i + 4) = b;
  } else {
    int idx = (bid - nb_cvt) * 256 + t;   // covers NPAD*D_DIM exactly
    int n = idx >> 8, k = idx & 255;
    float v = 0.f;
    if (n < 256) v = W_lin[k * 256 + n];
    else if (n < 512) v = W_res[k * 256 + (n - 256)];
    else if (n < 520) {
      int h = n - 512; float s = 0.f;
      #pragma unroll
      for (int c = 0; c < 32; ++c) s += W_lin[k * 256 + h * 32 + c] * att_l[h * 32 + c];
      v = s;
    } else if (n < 528) {
      int h = n - 520; float s = 0.f;
      #pragma unroll
      for (int c = 0; c < 32; ++c) s += W_lin[k * 256 + h * 32 + c] * att_r[h * 32 + c];
      v = s;
    }
    Bt[idx] = f2bf(v);
  }
}

// ---------------- standalone histogram (split from gemm) ----------------
// Round-2 counters disproved the hist|gemm fusion: 117 us at Occ 29.7%, MfmaUtil 5.3%,
// VALUBusy 8% -- hist blocks (dispatched first, dragging the GEMM's LDS allocation)
// gated the machine and the phases ran ~serially anyway. Standalone: no LDS ->
// 32 waves/CU of atomic latency hiding.
__global__ __launch_bounds__(256) void hist_kernel(
    const int* __restrict__ dst, int* __restrict__ cnt, int* __restrict__ rank, int E) {
  int base = (int)blockIdx.x * 2048 + threadIdx.x;
  #pragma unroll
  for (int u = 0; u < 8; ++u) {
    int e = base + u * 256;
    if (e < E) rank[e] = atomicAdd(&cnt[dst[e]], 1);   // 8 independent RMWs in flight
  }
}

// ---------------- scans ----------------
__global__ __launch_bounds__(256) void scan_partial(const int* __restrict__ cnt,
                                                    int* __restrict__ bsum, int N) {
  __shared__ int s[256];
  int t = threadIdx.x;
  int i = blockIdx.x * 256 + t;
  s[t] = (i < N) ? cnt[i] : 0;
  __syncthreads();
  for (int off = 128; off > 0; off >>= 1) {
    if (t < off) s[t] += s[t + off];
    __syncthreads();
  }
  if (t == 0) bsum[blockIdx.x] = s[0];
}

__global__ __launch_bounds__(256) void scan_top(int* __restrict__ bsum, int nb) {
  __shared__ int s[256];
  int t = threadIdx.x;
  int v = (t < nb) ? bsum[t] : 0;
  s[t] = v;
  __syncthreads();
  for (int off = 1; off < 256; off <<= 1) {
    int u = (t >= off) ? s[t - off] : 0;
    __syncthreads();
    s[t] += u;
    __syncthreads();
  }
  if (t < nb) bsum[t] = s[t] - v;   // exclusive
}

// scan_apply v2: also fills dstA[pos] = node for pos in [excl, excl+v) when mode==1.
// Positions are contiguous per node -> near-sequential 4B writes (6.4 MB total).
__global__ __launch_bounds__(256) void scan_apply(const int* __restrict__ cnt,
                                                  const int* __restrict__ bsum,
                                                  int* __restrict__ row_ptr,
                                                  int* __restrict__ dstA, int mode, int N) {
  __shared__ int s[256];
  int t = threadIdx.x;
  int i = blockIdx.x * 256 + t;
  int v = (i < N) ? cnt[i] : 0;
  s[t] = v;
  __syncthreads();
  for (int off = 1; off < 256; off <<= 1) {
    int u = (t >= off) ? s[t - off] : 0;
    __syncthreads();
    s[t] += u;
    __syncthreads();
  }
  int excl = bsum[blockIdx.x] + s[t] - v;
  if (i < N) {
    row_ptr[i] = excl;
    if (mode) {
      int e2 = excl + v;
      for (int j = excl; j < e2; ++j) dstA[j] = i;
    }
    if (i == N - 1) row_ptr[N] = excl + v;
  }
}

// ---------------- bf16 MFMA GEMM (pure, BK=64, XOR-swizzled LDS) ----------------
// Swizzle discipline (rule #21): global_load_lds writes LINEARLY (base+lane*16),
// so the swizzle is applied by permuting the per-lane GLOBAL source column
// (koff ^ (row&7)) and applying the SAME involution on the ds_read column.
__global__ __launch_bounds__(256) void gemm_kernel(
    const unsigned short* __restrict__ A,   // feat bf16 [M][256]
    const unsigned short* __restrict__ Bt,  // [640][256]
    float* __restrict__ out, unsigned short* __restrict__ xbf,
    float* __restrict__ alpha_l, float* __restrict__ alpha_r, int M, int gx) {
  __shared__ unsigned short As[128 * 64];
  __shared__ unsigned short Bs[128 * 64];

  int tid  = threadIdx.x;
  int w    = tid >> 6, lane = tid & 63;
  int gb   = (int)blockIdx.x;
  int bm   = (gb % gx) * 128, bn = (gb / gx) * 128;
  int wm   = (w & 1) * 64, wn = (w >> 1) * 64;
  int l16  = lane & 15, quad = lane >> 4;

  f32x4 acc[4][4] = {};

  int sr8     = lane >> 3;                       // row within 8-row staging group
  int koff_sw = (((lane & 7) ^ sr8) * 8);        // pre-swizzled source column (elements)

  for (int k0 = 0; k0 < 256; k0 += 64) {
    #pragma unroll
    for (int j = 0; j < 4; ++j) {
      int rbase = w * 32 + j * 8;
      int rga = bm + rbase + sr8; if (rga > M - 1) rga = M - 1;   // clamp (stores guarded)
      gld16(A  + (size_t)rga * 256 + k0 + koff_sw, &As[rbase * 64]);
      gld16(Bt + (size_t)(bn + rbase + sr8) * 256 + k0 + koff_sw, &Bs[rbase * 64]);
    }
    __syncthreads();
    #pragma unroll
    for (int kk = 0; kk < 64; kk += 32) {
      bf16x8 a[4], b[4];
      #pragma unroll
      for (int mi = 0; mi < 4; ++mi) {
        int r = wm + mi * 16 + l16;
        int col = (kk * 2 + quad * 16) ^ ((r & 7) << 4);   // byte col, same involution
        a[mi] = *(const bf16x8*)((const char*)&As[r * 64] + col);
      }
      #pragma unroll
      for (int ni = 0; ni < 4; ++ni) {
        int r = wn + ni * 16 + l16;
        int col = (kk * 2 + quad * 16) ^ ((r & 7) << 4);
        b[ni] = *(const bf16x8*)((const char*)&Bs[r * 64] + col);
      }
      #pragma unroll
      for (int mi = 0; mi < 4; ++mi)
        #pragma unroll
        for (int ni = 0; ni < 4; ++ni)
          acc[mi][ni] = __builtin_amdgcn_mfma_f32_16x16x32_bf16(a[mi], b[ni], acc[mi][ni], 0, 0, 0);
    }
    __syncthreads();
  }

  #pragma unroll
  for (int mi = 0; mi < 4; ++mi) {
    #pragma unroll
    for (int r = 0; r < 4; ++r) {
      int row = bm + wm + mi * 16 + quad * 4 + r;
      if (row >= M) continue;
      #pragma unroll
      for (int ni = 0; ni < 4; ++ni) {
        int n = bn + wn + ni * 16 + l16;
        float v = acc[mi][ni][r];
        if (n < 256)      xbf[(size_t)row * 256 + n] = f2bf(v);
        else if (n < 512) out[(size_t)row * 256 + (n - 256)] = v;
        else if (n < 520) alpha_l[row * 8 + (n - 512)] = v;
        else if (n < 528) alpha_r[row * 8 + (n - 520)] = v;
      }
    }
  }
}

// ---------------- scatter (atomic-free, rank-based) — cheap 8 B/edge payload ----------------
__global__ __launch_bounds__(256) void scatter_kernel(
    const int* __restrict__ eidx, const float* __restrict__ ew,
    const int* __restrict__ row_ptr, const int* __restrict__ rank,
    int2* __restrict__ pairs, int E) {
  int e = blockIdx.x * 256 + threadIdx.x;
  if (e < E) {
    int d = eidx[E + e];
    int pos = row_ptr[d] + rank[e];
    int2 p; p.x = eidx[e]; p.y = __float_as_int(ew[e]);
    pairs[pos] = p;
  }
}

// ---------------- score: position-ordered, all-coalesced pexp production ----------------
// Round-2 lesson: pexp precompute makes agg fast, but producing it with scattered writes
// is too expensive. Here we iterate POSITIONS: pairs[t] + dstA[t] are coalesced streams,
// alpha_r[d] is read in monotonic-d order (effectively sequential), alpha_l[s] is the
// only true gather (1.6 MB, L2-resident), and the 16 B pexp write is coalesced.
__global__ __launch_bounds__(256) void score_kernel(
    const int2* __restrict__ pairs, const int* __restrict__ dstA,
    const float* __restrict__ alpha_l, const float* __restrict__ alpha_r,
    unsigned short* __restrict__ pexp, int E) {
  int t = blockIdx.x * 256 + threadIdx.x;
  if (t >= E) return;
  int2 pr = pairs[t];
  int d = dstA[t];
  float w = __int_as_float(pr.y);
  float4 al0 = *(const float4*)(alpha_l + (size_t)pr.x * 8);
  float4 al1 = *(const float4*)(alpha_l + (size_t)pr.x * 8 + 4);
  float4 ar0 = *(const float4*)(alpha_r + (size_t)d * 8);
  float4 ar1 = *(const float4*)(alpha_r + (size_t)d * 8 + 4);
  float a[8] = {al0.x + ar0.x, al0.y + ar0.y, al0.z + ar0.z, al0.w + ar0.w,
                al1.x + ar1.x, al1.y + ar1.y, al1.z + ar1.z, al1.w + ar1.w};
  unsigned short pb[8];
  #pragma unroll
  for (int h = 0; h < 8; ++h) {
    float v = w * a[h];
    v = (v > 0.f) ? v : 0.2f * v;        // leaky_relu(0.2)
    pb[h] = f2bf(__expf(v));             // softmax numerator (scores bounded, no max-shift)
  }
  ushort4 o0, o1;
  o0.x = pb[0]; o0.y = pb[1]; o0.z = pb[2]; o0.w = pb[3];
  o1.x = pb[4]; o1.y = pb[5]; o1.z = pb[6]; o1.w = pb[7];
  *(ushort4*)(pexp + (size_t)t * 8) = o0;
  *(ushort4*)(pexp + (size_t)t * 8 + 4) = o1;
}

// ---------------- agg v5: 2 waves per dst node, gather-free score path ----------------
// mode 1 (normal): loop reads pairs.x (stream), pexp (stream), xbf (the only gather) --
// the round-2-proven fast form. mode 0 (workspace-fallback): round-3 in-loop alpha path.
__global__ __launch_bounds__(256) void agg_kernel(
    const int* __restrict__ row_ptr, const int2* __restrict__ pairs,
    const unsigned short* __restrict__ pexp,
    const float* __restrict__ alpha_l, const float* __restrict__ alpha_r,
    const unsigned short* __restrict__ xbf, float* __restrict__ out, int mode, int N) {
  __shared__ float red[2][64][6];        // [node-in-block][lane][l,ac0..3] (+pad)
  int nin  = threadIdx.x >> 7;           // node within block
  int wv   = (threadIdx.x >> 6) & 1;     // wave within node
  int lane = threadIdx.x & 63;
  int node = blockIdx.x * 2 + nin;
  bool active = node < N;
  int h  = lane >> 3;                    // head for this lane's 4 channels
  int cb = lane << 2;                    // channel base (0..252)

  float l = 0.f, ac0 = 0.f, ac1 = 0.f, ac2 = 0.f, ac3 = 0.f;

  if (active) {
    int beg = row_ptr[node], end = row_ptr[node + 1];
    if (beg < end) {
      int last = end - 1;
      const unsigned short* xb = xbf + cb;
      if (mode) {
        for (int jg = beg + wv * 4; jg < end; jg += 8) {
          int s[4]; float pv[4];
          #pragma unroll
          for (int u = 0; u < 4; ++u) {
            int t = jg + u; t = (t < last) ? t : last;   // clamp (masked below)
            s[u]  = pairs[t].x;
            pv[u] = bf2f(pexp[(size_t)t * 8 + h]);
          }
          ushort4 xv[4];
          #pragma unroll
          for (int u = 0; u < 4; ++u)
            xv[u] = *(const ushort4*)(xb + ((size_t)s[u] << 8));
          #pragma unroll
          for (int u = 0; u < 4; ++u) {
            float p = (jg + u < end) ? pv[u] : 0.f;      // mask tail
            l += p;
            ac0 = fmaf(p, bf2f(xv[u].x), ac0);
            ac1 = fmaf(p, bf2f(xv[u].y), ac1);
            ac2 = fmaf(p, bf2f(xv[u].z), ac2);
            ac3 = fmaf(p, bf2f(xv[u].w), ac3);
          }
        }
      } else {
        float arv = alpha_r[node * 8 + h];
        for (int jg = beg + wv * 4; jg < end; jg += 8) {
          int2 q[4];
          #pragma unroll
          for (int u = 0; u < 4; ++u) {
            int t = jg + u; t = (t < last) ? t : last;
            q[u] = pairs[t];
          }
          float al[4];
          #pragma unroll
          for (int u = 0; u < 4; ++u) al[u] = alpha_l[(size_t)q[u].x * 8 + h];
          ushort4 xv[4];
          #pragma unroll
          for (int u = 0; u < 4; ++u)
            xv[u] = *(const ushort4*)(xb + ((size_t)q[u].x << 8));
          #pragma unroll
          for (int u = 0; u < 4; ++u) {
            float a = __int_as_float(q[u].y) * (al[u] + arv);
            a = (a > 0.f) ? a : 0.2f * a;
            float p = __expf(a);
            p = (jg + u < end) ? p : 0.f;
            l += p;
            ac0 = fmaf(p, bf2f(xv[u].x), ac0);
            ac1 = fmaf(p, bf2f(xv[u].y), ac1);
            ac2 = fmaf(p, bf2f(xv[u].z), ac2);
            ac3 = fmaf(p, bf2f(xv[u].w), ac3);
          }
        }
      }
    }
  }

  if (wv == 1) {
    red[nin][lane][0] = l;
    red[nin][lane][1] = ac0; red[nin][lane][2] = ac1;
    red[nin][lane][3] = ac2; red[nin][lane][4] = ac3;
  }
  __syncthreads();
  if (active && wv == 0) {
    l   += red[nin][lane][0];
    ac0 += red[nin][lane][1]; ac1 += red[nin][lane][2];
    ac2 += red[nin][lane][3]; ac3 += red[nin][lane][4];
    float r = 1.0f / (l + 1e-16f);
    float o0 = ac0 * r, o1 = ac1 * r, o2 = ac2 * r, o3 = ac3 * r;
    o0 = (o0 > 0.f) ? o0 : expm1f(o0);  // elu
    o1 = (o1 > 0.f) ? o1 : expm1f(o1);
    o2 = (o2 > 0.f) ? o2 : expm1f(o2);
    o3 = (o3 > 0.f) ? o3 : expm1f(o3);
    float4* op = (float4*)(out + ((size_t)node << 8) + cb);
    float4 res = *op;                    // residual written by gemm epilogue
    res.x += o0; res.y += o1; res.z += o2; res.w += o3;
    *op = res;
  }
}

extern "C" void kernel_launch(void* const* d_in, const int* in_sizes, int n_in,
                              void* d_out, int out_size, void* d_ws, size_t ws_size,
                              hipStream_t stream) {
  const float* feat  = (const float*)d_in[0];
  const float* ew    = (const float*)d_in[1];
  const float* W_lin = (const float*)d_in[2];
  const float* att_l = (const float*)d_in[3];
  const float* att_r = (const float*)d_in[4];
  const float* W_res = (const float*)d_in[5];
  const int*   eidx  = (const int*)d_in[6];
  float* out = (float*)d_out;

  int N = in_sizes[0] / D_DIM;
  int E = in_sizes[1];

  char* p = (char*)d_ws;
  auto alloc = [&](size_t bytes) {
    char* r = p; p += (bytes + 255) & ~(size_t)255; return r;
  };
  unsigned short* xbf  = (unsigned short*)alloc((size_t)N * 256 * 2);   // 25.6 MB
  unsigned short* fb   = (unsigned short*)alloc((size_t)N * 256 * 2);   // 25.6 MB
  float* alpha_l       = (float*)alloc((size_t)N * 8 * 4);
  float* alpha_r       = (float*)alloc((size_t)N * 8 * 4);
  unsigned short* Bt   = (unsigned short*)alloc((size_t)NPAD * D_DIM * 2);
  int*   row_ptr       = (int*)alloc((size_t)(N + 1) * 4);
  int*   cnt           = (int*)alloc((size_t)N * 4);
  int*   rank          = (int*)alloc((size_t)E * 4);
  int*   bsum          = (int*)alloc(1024);
  int2*  pairs         = (int2*)alloc((size_t)E * 8);                   // 12.8 MB
  char*  opt_base      = p;
  int*   dstA          = (int*)alloc((size_t)E * 4);                    // 6.4 MB
  unsigned short* pexp = (unsigned short*)alloc((size_t)E * 8 * 2);     // 25.6 MB

  int mode = 1;
  if ((size_t)(p - (char*)d_ws) > ws_size) {
    // retry with pexp aliased onto fb (fb dead after gemm; score runs after gemm)
    p = opt_base;
    dstA = (int*)alloc((size_t)E * 4);
    pexp = fb;
    if ((size_t)(p - (char*)d_ws) > ws_size) {
      mode = 0;                                 // round-3 fallback: in-loop alpha path
      if ((size_t)((char*)(pairs + E) - (char*)d_ws) > ws_size)
        pairs = (int2*)fb;                      // proven round-3 alias
    }
  }

  int nb      = (N + 255) / 256;
  int nb_cvt  = (N * 256 / 8 + 255) / 256;
  int nb_prep = NPAD * D_DIM / 256;
  int nb_hist = (E + 2047) / 2048;    // 8 edges/thread
  int nb_scat = (E + 255) / 256;
  int gx = (N + 127) / 128;
  int gemm_blocks = gx * (NPAD / 128);

  hipMemsetAsync(cnt, 0, (size_t)N * 4, stream);

  setup_cvt_prep<<<nb_cvt + nb_prep, 256, 0, stream>>>(
      feat, fb, W_lin, W_res, att_l, att_r, Bt, N * 256, nb_cvt);

  hist_kernel<<<nb_hist, 256, 0, stream>>>(eidx + E, cnt, rank, E);

  gemm_kernel<<<gemm_blocks, 256, 0, stream>>>(
      fb, Bt, out, xbf, alpha_l, alpha_r, N, gx);

  scan_partial<<<nb, 256, 0, stream>>>(cnt, bsum, N);
  scan_top<<<1, 256, 0, stream>>>(bsum, nb);
  scan_apply<<<nb, 256, 0, stream>>>(cnt, bsum, row_ptr, dstA, mode, N);

  scatter_kernel<<<nb_scat, 256, 0, stream>>>(eidx, ew, row_ptr, rank, pairs, E);

  if (mode)
    score_kernel<<<nb_scat, 256, 0, stream>>>(pairs, dstA, alpha_l, alpha_r, pexp, E);

  agg_kernel<<<(N + 1) / 2, 256, 0, stream>>>(
      row_ptr, pairs, pexp, alpha_l, alpha_r, xbf, out, mode, N);
}